// Round 1
// baseline (459.957 us; speedup 1.0000x reference)
//
#include <hip/hip_runtime.h>
#include <stdint.h>

#define NCLS  21
#define CDIM  256
#define HWSZ  16384
#define NPIX  131072
#define EPSV  1e-6f
#define NEGV  -1e30f
#define CAP_W 4096
#define CAP_S 16384
#define KSEL  256
#define NCC   8            // channel chunks in k1a
#define CCH   (CDIM/NCC)   // 32 channels per chunk
#define NPART 8            // strong top-k partitions per class
#define NBLK2 (NPIX/512)   // 256 pixel groups (512 pixels each)
#define WPAR  8            // kw_sum partitions

__device__ __forceinline__ uint64_t pack_key(float v, unsigned idx) {
  unsigned u = __float_as_uint(v);
  u = (u & 0x80000000u) ? ~u : (u | 0x80000000u);  // order-preserving map
  return ((uint64_t)(~u) << 32) | (uint64_t)idx;   // ascending key == descending value, tie -> low idx
}

// ---------------- K0: normalize prototypes, zero accumulators ----------------
__global__ void k0_init(const float* __restrict__ mb, float* pn, float* wsum) {
  int k = blockIdx.x, t = threadIdx.x;
  float v = mb[k * CDIM + t];
  float s = v * v;
  for (int o = 32; o > 0; o >>= 1) s += __shfl_down(s, o, 64);
  __shared__ float wsh[4];
  int wid = t >> 6, lane = t & 63;
  if (lane == 0) wsh[wid] = s;
  __syncthreads();
  float tot = wsh[0] + wsh[1] + wsh[2] + wsh[3];
  float inv = 1.0f / fmaxf(sqrtf(tot), EPSV);
  pn[k * CDIM + t] = v * inv;
  wsum[k * CDIM + t] = 0.0f;
}

// ---------------- K1a: streaming pass — pure load+FMA, no in-loop atomics ----------------
// grid: (NBLK2, NCC). Each thread: 2 pixels, CCH channels.
__global__ void k1a_stream(const float* __restrict__ fw, const float* __restrict__ fs,
                           const float* __restrict__ prob, const int* __restrict__ seg,
                           const int* __restrict__ ign, const float* __restrict__ pn,
                           float* part, int* cnts) {
  __shared__ float pnT[CCH * NCLS];          // [c_local][k]
  __shared__ int hs[NCLS], hw2[NCLS];
  int t = threadIdx.x;
  int pg = blockIdx.x;   // pixel group (512 pixels)
  int cc = blockIdx.y;   // channel chunk
  int c0 = cc * CCH;
  for (int i = t; i < CCH * NCLS; i += 256) {
    int c = i / NCLS, k = i % NCLS;
    pnT[i] = pn[k * CDIM + c0 + c];
  }
  if (cc == 0) {
    for (int i = t; i < NCLS; i += 256) { hs[i] = 0; hw2[i] = 0; }
  }
  __syncthreads();

  int n0 = pg * 512 + t * 2;
  int b = n0 >> 14, hw = n0 & (HWSZ - 1);
  int2   sg = *(const int2*)(seg + n0);
  int2   ig = *(const int2*)(ign + n0);
  float2 pr = *(const float2*)(prob + n0);
  if (cc == 0) {
    bool v0 = (ig.x != 255), v1 = (ig.y != 255);
    if (v0) atomicAdd(&hs[sg.x], 1);
    if (v1) atomicAdd(&hs[sg.y], 1);
    if (v0 && pr.x > 0.95f) atomicAdd(&hw2[sg.x], 1);
    if (v1 && pr.y > 0.95f) atomicAdd(&hw2[sg.y], 1);
  }

  const float* fwp = fw + ((size_t)b * CDIM + c0) * HWSZ + hw;
  const float* fsp = fs + ((size_t)b * CDIM + c0) * HWSZ + hw;

  float2 dw = {0,0}, nw = {0,0}, dsv = {0,0}, ns = {0,0};
#pragma unroll 8
  for (int cl = 0; cl < CCH; ++cl) {
    float2 a = *(const float2*)(fwp + (size_t)cl * HWSZ);
    float2 s = *(const float2*)(fsp + (size_t)cl * HWSZ);
    float p0 = pnT[cl * NCLS + sg.x];
    float p1 = pnT[cl * NCLS + sg.y];
    dw.x = fmaf(a.x, p0, dw.x); nw.x = fmaf(a.x, a.x, nw.x);
    dw.y = fmaf(a.y, p1, dw.y); nw.y = fmaf(a.y, a.y, nw.y);
    dsv.x = fmaf(s.x, p0, dsv.x); ns.x = fmaf(s.x, s.x, ns.x);
    dsv.y = fmaf(s.y, p1, dsv.y); ns.y = fmaf(s.y, s.y, ns.y);
  }
  float4* pp = (float4*)part + ((size_t)cc * NPIX + n0);
  pp[0] = make_float4(dw.x, nw.x, dsv.x, ns.x);
  pp[1] = make_float4(dw.y, nw.y, dsv.y, ns.y);

  if (cc == 0) {
    __syncthreads();
    for (int i = t; i < NCLS; i += 256) {
      cnts[pg * NCLS + i] = hs[i];
      cnts[NBLK2 * NCLS + pg * NCLS + i] = hw2[i];
    }
  }
}

// ---------------- KS: exclusive scan of per-block class counts ----------------
__global__ void ks_scan(const int* __restrict__ cnts, int* offs, int* scnt, int* wcnt) {
  __shared__ int L[2 * NBLK2 * NCLS];
  int t = threadIdx.x;
  for (int i = t; i < 2 * NBLK2 * NCLS; i += 256) L[i] = cnts[i];
  __syncthreads();
  if (t < 2 * NCLS) {
    int q = t % NCLS;
    int typ = t / NCLS;  // 0 strong, 1 weak
    int base = typ * NBLK2 * NCLS;
    int run = 0;
    for (int b2 = 0; b2 < NBLK2; ++b2) {
      int v = L[base + b2 * NCLS + q];
      L[base + b2 * NCLS + q] = run;
      run += v;
    }
    if (typ == 0) scnt[q] = run; else wcnt[q] = run;
  }
  __syncthreads();
  for (int i = t; i < 2 * NBLK2 * NCLS; i += 256) offs[i] = L[i];
}

// ---------------- K1b: combine partials, compute sims, write keys at precomputed offsets ----------------
__global__ void k1b_write(const float* __restrict__ part, const float* __restrict__ prob,
                          const int* __restrict__ seg, const int* __restrict__ ign,
                          const int* __restrict__ offs, uint64_t* wkeys, uint64_t* skeys) {
  __shared__ int ls[NCLS], lw[NCLS];
  int t = threadIdx.x, pg = blockIdx.x;
  if (t < NCLS) {
    ls[t] = offs[pg * NCLS + t];
    lw[t] = offs[NBLK2 * NCLS + pg * NCLS + t];
  }
  __syncthreads();
  int n0 = pg * 512 + t * 2;
  int2   sg = *(const int2*)(seg + n0);
  int2   ig = *(const int2*)(ign + n0);
  float2 pr = *(const float2*)(prob + n0);
  float dw[2] = {0,0}, nw[2] = {0,0}, ds[2] = {0,0}, ns[2] = {0,0};
#pragma unroll
  for (int cc = 0; cc < NCC; ++cc) {
    const float4* pp = (const float4*)part + ((size_t)cc * NPIX + n0);
#pragma unroll
    for (int i = 0; i < 2; ++i) {
      float4 v = pp[i];
      dw[i] += v.x; nw[i] += v.y; ds[i] += v.z; ns[i] += v.w;
    }
  }
  int   sga[2] = {sg.x, sg.y};
  int   iga[2] = {ig.x, ig.y};
  float pra[2] = {pr.x, pr.y};
#pragma unroll
  for (int i = 0; i < 2; ++i) {
    if (iga[i] != 255) {
      int q = sga[i];
      float sim_s = ds[i] / fmaxf(sqrtf(ns[i]), EPSV);
      int pos = atomicAdd(&ls[q], 1);
      if (pos < CAP_S) skeys[(size_t)q * CAP_S + pos] = pack_key(-sim_s, (unsigned)(n0 + i));
      if (pra[i] > 0.95f) {
        float sim_w = dw[i] / fmaxf(sqrtf(nw[i]), EPSV);
        int pw = atomicAdd(&lw[q], 1);
        if (pw < CAP_W) wkeys[(size_t)q * CAP_W + pw] = pack_key(sim_w, (unsigned)(n0 + i));
      }
    }
  }
}

// ---------------- KW: wsum from confident-pixel list (replaces k1a in-loop atomics) ----------------
// grid (NCLS, WPAR); thread t = channel.
__global__ void kw_sum(const float* __restrict__ fw, const uint64_t* __restrict__ wkeys,
                       const int* __restrict__ wcnt, float* wsum) {
  int k = blockIdx.x, p = blockIdx.y, t = threadIdx.x;
  int cnt = min(wcnt[k], CAP_W);
  float acc = 0.0f;
  for (int i = p; i < cnt; i += WPAR) {
    unsigned idx = (unsigned)(wkeys[(size_t)k * CAP_W + i] & 0xFFFFFFFFull);
    int b = idx >> 14, hw = idx & (HWSZ - 1);
    acc += fw[((size_t)(b * CDIM) + t) * HWSZ + hw];
  }
  if (acc != 0.0f) atomicAdd(&wsum[k * CDIM + t], acc);
}

// ---------------- top-256 select (cutoff-filtered bitonic), 256 threads ----------------
__device__ void select_topk(const uint64_t* __restrict__ list, int cnt,
                            uint64_t* T, uint64_t* P, int* pcnt, int* woff) {
  int t = threadIdx.x;
  T[t] = ~0ull;
  if (t == 0) *pcnt = 0;
  __syncthreads();
  for (int base = 0; base < cnt; base += 256) {
    uint64_t key = (base + t < cnt) ? list[base + t] : ~0ull;
    uint64_t cutoff = T[KSEL - 1];
    bool pred = key < cutoff;
    unsigned long long mask = __ballot(pred);
    int wid = t >> 6, lane = t & 63;
    if (lane == 0) woff[wid] = __popcll(mask);
    int prefix = __popcll(mask & ((1ull << lane) - 1ull));
    __syncthreads();
    int off = 0;
    for (int w2 = 0; w2 < wid; ++w2) off += woff[w2];
    int total = woff[0] + woff[1] + woff[2] + woff[3];
    int old = *pcnt;
    if (pred) P[old + off + prefix] = key;
    int newc = old + total;
    __syncthreads();
    if (t == 0) *pcnt = newc;
    bool last = (base + 256 >= cnt);
    if (newc >= KSEL || (last && newc > 0)) {
      for (int i2 = t; i2 < 2 * KSEL; i2 += 256)
        if (i2 >= newc) P[i2] = ~0ull;
      for (unsigned size = 2; size <= 2 * KSEL; size <<= 1) {
        for (unsigned stride = size >> 1; stride > 0; stride >>= 1) {
          __syncthreads();
          unsigned lo = stride - 1;
          unsigned i = (((unsigned)t & ~lo) << 1) | ((unsigned)t & lo);
          unsigned j = i | stride;
          uint64_t a = P[i], b = P[j];
          bool up = ((i & size) == 0);
          if ((a > b) == up) { P[i] = b; P[j] = a; }
        }
      }
      __syncthreads();
      uint64_t a = T[t], b = P[KSEL - 1 - t];
      T[t] = a < b ? a : b;
      for (unsigned stride = KSEL / 2; stride > 0; stride >>= 1) {
        __syncthreads();
        if (((unsigned)t & stride) == 0) {
          uint64_t x = T[t], y = T[t + stride];
          if (x > y) { T[t] = y; T[t + stride] = x; }
        }
      }
      __syncthreads();
      if (t == 0) *pcnt = 0;
      __syncthreads();
    } else {
      __syncthreads();
    }
  }
}

// ---------------- K2: weak top-16 (full) + strong top-256 (partitioned) ----------------
__global__ void k2_topk(const uint64_t* __restrict__ wkeys, const uint64_t* __restrict__ skeys,
                        const int* wcnt, const int* scnt,
                        uint64_t* psel, int* idxw, int* kwv, int* nwv) {
  __shared__ uint64_t T[KSEL];
  __shared__ uint64_t P[2 * KSEL];
  __shared__ int pcnt;
  __shared__ int woff[4];
  int bid = blockIdx.x, t = threadIdx.x;
  if (bid < NCLS * NPART) {
    int k = bid / NPART, p = bid % NPART;
    int cnt = min(scnt[k], CAP_S);
    int chunk = (cnt + NPART - 1) / NPART;
    int lo = p * chunk;
    int hi = min(lo + chunk, cnt);
    int c = hi > lo ? hi - lo : 0;
    select_topk(skeys + (size_t)k * CAP_S + lo, c, T, P, &pcnt, woff);
    psel[((size_t)k * NPART + p) * KSEL + t] = T[t];
  } else {
    int k = bid - NCLS * NPART;
    int cnt_total = wcnt[k];
    int cnt = min(cnt_total, CAP_W);
    select_topk(wkeys + (size_t)k * CAP_W, cnt, T, P, &pcnt, woff);
    if (t < 16) idxw[k * 16 + t] = (int)(unsigned)(T[t] & 0xFFFFFFFFull);
    if (t == 0) { nwv[k] = cnt_total; kwv[k] = min(cnt_total, 16); }
  }
}

// ---------------- K2m: merge 8 sorted partition results -> final strong top-256 ----------------
__global__ void k2m_merge(const uint64_t* __restrict__ psel, const int* scnt,
                          int* idxs, int* ksv, int* nsv) {
  int k = blockIdx.x, t = threadIdx.x;
  __shared__ uint64_t M[NPART * KSEL];  // 2048
  for (int i = t; i < NPART * KSEL; i += 256) M[i] = psel[(size_t)k * NPART * KSEL + i];
  for (unsigned size = 2; size <= NPART * KSEL; size <<= 1) {
    for (unsigned stride = size >> 1; stride > 0; stride >>= 1) {
      __syncthreads();
      for (unsigned q = t; q < NPART * KSEL / 2; q += 256) {
        unsigned lo = stride - 1;
        unsigned i = ((q & ~lo) << 1) | (q & lo);
        unsigned j = i | stride;
        uint64_t a = M[i], b = M[j];
        bool up = ((i & size) == 0);
        if ((a > b) == up) { M[i] = b; M[j] = a; }
      }
    }
  }
  __syncthreads();
  idxs[k * KSEL + t] = (int)(unsigned)(M[t] & 0xFFFFFFFFull);
  if (t == 0) { int c = scnt[k]; nsv[k] = c; ksv[k] = c < KSEL ? c : KSEL; }
}

// ---------------- K3a: gather + normalize selected vectors into dense buffers ----------------
// grid ((KSEL+16)/4, NCLS): 4 slots per block -> 4 independent strided loads per thread.
__global__ void k3a_gather(const float* __restrict__ fw, const float* __restrict__ fs,
                           const int* __restrict__ idxw, const int* __restrict__ idxs,
                           const int* __restrict__ kwv, const int* __restrict__ ksv,
                           float* dw_dense, float* ds_dense) {
  int k = blockIdx.y;
  int s0 = blockIdx.x * 4;
  int t = threadIdx.x;
  int wid = t >> 6, lane = t & 63;
  float v[4];
  bool strong[4];
  int slot_[4];
#pragma unroll
  for (int j = 0; j < 4; ++j) {
    int slot = s0 + j;
    slot_[j] = slot;
    strong[j] = slot < KSEL;
    bool ok;
    int n = 0;
    if (strong[j]) {
      ok = slot < ksv[k];
      if (ok) n = idxs[k * KSEL + slot];
    } else {
      int i = slot - KSEL;
      ok = i < kwv[k];
      int rank = i > 0 ? i - 1 : 0;  // ranks = max(arange(16)-1, 0)
      if (ok) n = idxw[k * 16 + rank];
    }
    v[j] = 0.0f;
    if (ok) {
      int b = n >> 14, hw = n & (HWSZ - 1);
      const float* f = strong[j] ? fs : fw;
      v[j] = f[(size_t)(b * CDIM + t) * HWSZ + hw];
    }
  }
  __shared__ float wsh[4][4];  // [wave][slot]
  float s[4];
#pragma unroll
  for (int j = 0; j < 4; ++j) {
    s[j] = v[j] * v[j];
    for (int o = 32; o > 0; o >>= 1) s[j] += __shfl_down(s[j], o, 64);
  }
  if (lane == 0) {
#pragma unroll
    for (int j = 0; j < 4; ++j) wsh[wid][j] = s[j];
  }
  __syncthreads();
#pragma unroll
  for (int j = 0; j < 4; ++j) {
    float tot = wsh[0][j] + wsh[1][j] + wsh[2][j] + wsh[3][j];
    float inv = 1.0f / fmaxf(sqrtf(tot), EPSV);
    float out = v[j] * inv;
    if (strong[j]) ds_dense[((size_t)k * KSEL + slot_[j]) * CDIM + t] = out;
    else           dw_dense[((size_t)k * 16 + (slot_[j] - KSEL)) * CDIM + t] = out;
  }
}

// ---------------- K3b: cosm, per-row max, per-class sum ----------------
__global__ void k3b_loss(const float* __restrict__ dw_dense, const float* __restrict__ ds_dense,
                         const int* kwv, const int* ksv, const int* nwv, const int* nsv,
                         float* simsum, int* countk) {
  int k = blockIdx.x, t = threadIdx.x;
  int wid = t >> 6, lane = t & 63;
  __shared__ float wn[16 * CDIM];
  __shared__ float wred[4][16];
  for (int i = t; i < 16 * CDIM; i += 256) wn[i] = dw_dense[(size_t)k * 16 * CDIM + i];
  __syncthreads();
  int ks_ = ksv[k], kw_ = kwv[k];
  bool ok = (nwv[k] > 0) && (nsv[k] > 0);
  float dots[16];
#pragma unroll
  for (int i = 0; i < 16; ++i) dots[i] = 0.0f;
  bool jv = ok && (t < ks_);
  if (jv) {
    const float4* sp = (const float4*)(ds_dense + ((size_t)k * KSEL + t) * CDIM);
    for (int c4 = 0; c4 < CDIM / 4; ++c4) {
      float4 v = sp[c4];
#pragma unroll
      for (int i = 0; i < 16; ++i) {
        float4 w = ((const float4*)(wn + i * CDIM))[c4];
        dots[i] = fmaf(v.x, w.x, dots[i]);
        dots[i] = fmaf(v.y, w.y, dots[i]);
        dots[i] = fmaf(v.z, w.z, dots[i]);
        dots[i] = fmaf(v.w, w.w, dots[i]);
      }
    }
  }
#pragma unroll
  for (int i = 0; i < 16; ++i) {
    float v = jv ? dots[i] : NEGV;
    for (int o = 32; o > 0; o >>= 1) v = fmaxf(v, __shfl_down(v, o, 64));
    if (lane == 0) wred[wid][i] = v;
  }
  __syncthreads();
  if (t == 0) {
    float csum = 0.0f;
    for (int i = 0; i < kw_; ++i) {
      float m = fmaxf(fmaxf(wred[0][i], wred[1][i]), fmaxf(wred[2][i], wred[3][i]));
      csum += m;
    }
    simsum[k] = ok ? csum : 0.0f;
    countk[k] = ok ? ks_ : 0;
  }
}

// ---------------- K4: memory bank update + loss ----------------
__global__ void k4_final(const float* __restrict__ mb, const float* __restrict__ wsum,
                         const int* __restrict__ nwv, const float* __restrict__ simsum,
                         const int* __restrict__ countk, float* out) {
  int k = blockIdx.x, t = threadIdx.x;
  float p = mb[k * CDIM + t];
  float o = p;
  int nw = nwv[k];
  if (nw > 0) {
    float mean = wsum[k * CDIM + t] / (float)nw;
    o = 0.99f * p + 0.01f * mean;
  }
  out[1 + k * CDIM + t] = o;
  if (k == 0 && t == 0) {
    float ss = 0.0f;
    int cc = 0;
    for (int q = 0; q < NCLS; ++q) { ss += simsum[q]; cc += countk[q]; }
    out[0] = (cc > 0) ? (1.0f - ss / (float)cc) : 0.0f;
  }
}

extern "C" void kernel_launch(void* const* d_in, const int* in_sizes, int n_in,
                              void* d_out, int out_size, void* d_ws, size_t ws_size,
                              hipStream_t stream) {
  const float* fw   = (const float*)d_in[0];
  const float* fs   = (const float*)d_in[1];
  const float* prob = (const float*)d_in[2];
  const float* mb   = (const float*)d_in[3];
  const int*   seg  = (const int*)d_in[4];
  const int*   ign  = (const int*)d_in[5];
  float* out = (float*)d_out;

  char* ws = (char*)d_ws;
  size_t off = 0;
  auto alloc = [&](size_t bytes) -> char* {
    char* p = ws + off;
    off = (off + bytes + 255) & ~(size_t)255;
    return p;
  };
  float*    pn       = (float*)alloc(NCLS * CDIM * 4);
  float*    wsum     = (float*)alloc(NCLS * CDIM * 4);
  int*      wcnt     = (int*)alloc(NCLS * 4);
  int*      scnt     = (int*)alloc(NCLS * 4);
  int*      idxw     = (int*)alloc(NCLS * 16 * 4);
  int*      idxs     = (int*)alloc(NCLS * KSEL * 4);
  int*      kwv      = (int*)alloc(NCLS * 4);
  int*      ksv      = (int*)alloc(NCLS * 4);
  int*      nwv      = (int*)alloc(NCLS * 4);
  int*      nsv      = (int*)alloc(NCLS * 4);
  float*    simsum   = (float*)alloc(NCLS * 4);
  int*      countk   = (int*)alloc(NCLS * 4);
  int*      cnts     = (int*)alloc(2 * NBLK2 * NCLS * 4);
  int*      offs     = (int*)alloc(2 * NBLK2 * NCLS * 4);
  uint64_t* wkeys    = (uint64_t*)alloc((size_t)NCLS * CAP_W * 8);
  uint64_t* skeys    = (uint64_t*)alloc((size_t)NCLS * CAP_S * 8);
  uint64_t* psel     = (uint64_t*)alloc((size_t)NCLS * NPART * KSEL * 8);
  float*    dw_dense = (float*)alloc((size_t)NCLS * 16 * CDIM * 4);
  float*    ds_dense = (float*)alloc((size_t)NCLS * KSEL * CDIM * 4);
  float*    part     = (float*)alloc((size_t)NCC * NPIX * 4 * 4);  // 16.8 MB
  (void)in_sizes; (void)n_in; (void)out_size; (void)ws_size;

  k0_init<<<NCLS, 256, 0, stream>>>(mb, pn, wsum);
  k1a_stream<<<dim3(NBLK2, NCC), 256, 0, stream>>>(fw, fs, prob, seg, ign, pn,
                                                   part, cnts);
  ks_scan<<<1, 256, 0, stream>>>(cnts, offs, scnt, wcnt);
  k1b_write<<<NBLK2, 256, 0, stream>>>(part, prob, seg, ign, offs, wkeys, skeys);
  kw_sum<<<dim3(NCLS, WPAR), 256, 0, stream>>>(fw, wkeys, wcnt, wsum);
  k2_topk<<<NCLS * NPART + NCLS, 256, 0, stream>>>(wkeys, skeys, wcnt, scnt,
                                                   psel, idxw, kwv, nwv);
  k2m_merge<<<NCLS, 256, 0, stream>>>(psel, scnt, idxs, ksv, nsv);
  k3a_gather<<<dim3((KSEL + 16) / 4, NCLS), 256, 0, stream>>>(fw, fs, idxw, idxs, kwv, ksv,
                                                              dw_dense, ds_dense);
  k3b_loss<<<NCLS, 256, 0, stream>>>(dw_dense, ds_dense, kwv, ksv, nwv, nsv,
                                     simsum, countk);
  k4_final<<<NCLS, 256, 0, stream>>>(mb, wsum, nwv, simsum, countk, out);
}

// Round 2
// 403.097 us; speedup vs baseline: 1.1411x; 1.1411x over previous
//
#include <hip/hip_runtime.h>
#include <stdint.h>

#define NCLS  21
#define CDIM  256
#define HWSZ  16384
#define NPIX  131072
#define EPSV  1e-6f
#define NEGV  -1e30f
#define CAP_W 4096
#define CAP_S 16384
#define KSEL  256
#define NCC   8            // channel chunks in k1a
#define CCH   (CDIM/NCC)   // 32 channels per chunk
#define NPART 8            // strong top-k partitions per class
#define NBLK2 (NPIX/512)   // 256 pixel groups (512 pixels each) for count/k1b
#define P2    2048         // pixels per k1a block
#define NPG   (NPIX/P2)    // 64 pixel groups for k1a

__device__ __forceinline__ uint64_t pack_key(float v, unsigned idx) {
  unsigned u = __float_as_uint(v);
  u = (u & 0x80000000u) ? ~u : (u | 0x80000000u);  // order-preserving map
  return ((uint64_t)(~u) << 32) | (uint64_t)idx;   // ascending key == descending value, tie -> low idx
}

// ---------------- K0: normalize prototypes, zero accumulators ----------------
__global__ void k0_init(const float* __restrict__ mb, float* pn, float* wsum) {
  int k = blockIdx.x, t = threadIdx.x;
  float v = mb[k * CDIM + t];
  float s = v * v;
  for (int o = 32; o > 0; o >>= 1) s += __shfl_down(s, o, 64);
  __shared__ float wsh[4];
  int wid = t >> 6, lane = t & 63;
  if (lane == 0) wsh[wid] = s;
  __syncthreads();
  float tot = wsh[0] + wsh[1] + wsh[2] + wsh[3];
  float inv = 1.0f / fmaxf(sqrtf(tot), EPSV);
  pn[k * CDIM + t] = v * inv;
  wsum[k * CDIM + t] = 0.0f;
}

// ---------------- K1a: streaming pass — long contiguous runs ----------------
// grid: (NPG=64, NCC=8). Block owns 2048 pixels x 32 channels.
// Thread owns 8 pixels strided by 256 -> every load/store wave-contiguous,
// per (block,channel) contiguous run = 8KB (vs 2KB before).
__global__ __launch_bounds__(256, 2)
void k1a_stream(const float* __restrict__ fw, const float* __restrict__ fs,
                const float* __restrict__ prob, const int* __restrict__ seg,
                const int* __restrict__ ign, const float* __restrict__ pn,
                float* part, float* wsum) {
  __shared__ float pnT[CCH * NCLS];          // [c_local][k]
  __shared__ float wloc[NCLS * (CCH + 1)];   // [k][c_local], padded
  int t = threadIdx.x;
  int pg = blockIdx.x;   // 0..63 (2048-pixel group)
  int cc = blockIdx.y;   // 0..7 channel chunk
  int c0 = cc * CCH;
  for (int i = t; i < CCH * NCLS; i += 256) {
    int c = i / NCLS, k = i % NCLS;
    pnT[i] = pn[k * CDIM + c0 + c];
  }
  for (int i = t; i < NCLS * (CCH + 1); i += 256) wloc[i] = 0.0f;
  __syncthreads();

  int base = pg * P2;
  int b = base >> 14;                 // batch (P2 divides HWSZ)
  int hwb = (base & (HWSZ - 1)) + t;  // in-plane offset for this lane

  int sgv[8]; bool cf[8];
  float dw[8], nw[8], dsv[8], nsv[8];
#pragma unroll
  for (int i = 0; i < 8; ++i) {
    int px = base + i * 256 + t;
    sgv[i] = seg[px];
    int igv = ign[px];
    float prv = prob[px];
    cf[i] = (igv != 255) && (prv > 0.95f);
    dw[i] = nw[i] = dsv[i] = nsv[i] = 0.0f;
  }

  const float* fwp = fw + ((size_t)b * CDIM + c0) * HWSZ + hwb;
  const float* fsp = fs + ((size_t)b * CDIM + c0) * HWSZ + hwb;

#pragma unroll 4
  for (int c = 0; c < CCH; ++c) {
    size_t co = (size_t)c * HWSZ;
    float a[8], s8[8];
#pragma unroll
    for (int i = 0; i < 8; ++i) a[i] = fwp[co + i * 256];
#pragma unroll
    for (int i = 0; i < 8; ++i) s8[i] = fsp[co + i * 256];
#pragma unroll
    for (int i = 0; i < 8; ++i) {
      float p = pnT[c * NCLS + sgv[i]];
      dw[i]  = fmaf(a[i],  p,     dw[i]);
      nw[i]  = fmaf(a[i],  a[i],  nw[i]);
      dsv[i] = fmaf(s8[i], p,     dsv[i]);
      nsv[i] = fmaf(s8[i], s8[i], nsv[i]);
      if (cf[i]) atomicAdd(&wloc[sgv[i] * (CCH + 1) + c], a[i]);
    }
  }

  float4* pp = (float4*)part + (size_t)cc * NPIX + base + t;
#pragma unroll
  for (int i = 0; i < 8; ++i)
    pp[i * 256] = make_float4(dw[i], nw[i], dsv[i], nsv[i]);

  __syncthreads();
  for (int i = t; i < NCLS * CCH; i += 256) {
    int k = i / CCH, cl = i % CCH;
    float v = wloc[k * (CCH + 1) + cl];
    if (v != 0.0f) atomicAdd(&wsum[k * CDIM + c0 + cl], v);
  }
}

// ---------------- K1c: per-group class histograms (seg/ign/prob only) ----------------
__global__ void k1c_count(const float* __restrict__ prob, const int* __restrict__ seg,
                          const int* __restrict__ ign, int* cnts) {
  __shared__ int hs[NCLS], hw2[NCLS];
  int t = threadIdx.x, pg = blockIdx.x;
  for (int i = t; i < NCLS; i += 256) { hs[i] = 0; hw2[i] = 0; }
  __syncthreads();
  int n0 = pg * 512 + t * 2;
  int2   sg = *(const int2*)(seg + n0);
  int2   ig = *(const int2*)(ign + n0);
  float2 pr = *(const float2*)(prob + n0);
  bool v0 = (ig.x != 255), v1 = (ig.y != 255);
  if (v0) atomicAdd(&hs[sg.x], 1);
  if (v1) atomicAdd(&hs[sg.y], 1);
  if (v0 && pr.x > 0.95f) atomicAdd(&hw2[sg.x], 1);
  if (v1 && pr.y > 0.95f) atomicAdd(&hw2[sg.y], 1);
  __syncthreads();
  for (int i = t; i < NCLS; i += 256) {
    cnts[pg * NCLS + i] = hs[i];
    cnts[NBLK2 * NCLS + pg * NCLS + i] = hw2[i];
  }
}

// ---------------- KS: exclusive scan of per-block class counts ----------------
__global__ void ks_scan(const int* __restrict__ cnts, int* offs, int* scnt, int* wcnt) {
  __shared__ int L[2 * NBLK2 * NCLS];
  int t = threadIdx.x;
  for (int i = t; i < 2 * NBLK2 * NCLS; i += 256) L[i] = cnts[i];
  __syncthreads();
  if (t < 2 * NCLS) {
    int q = t % NCLS;
    int typ = t / NCLS;  // 0 strong, 1 weak
    int base = typ * NBLK2 * NCLS;
    int run = 0;
    for (int b2 = 0; b2 < NBLK2; ++b2) {
      int v = L[base + b2 * NCLS + q];
      L[base + b2 * NCLS + q] = run;
      run += v;
    }
    if (typ == 0) scnt[q] = run; else wcnt[q] = run;
  }
  __syncthreads();
  for (int i = t; i < 2 * NBLK2 * NCLS; i += 256) offs[i] = L[i];
}

// ---------------- K1b: combine partials, compute sims, write keys at precomputed offsets ----------------
__global__ void k1b_write(const float* __restrict__ part, const float* __restrict__ prob,
                          const int* __restrict__ seg, const int* __restrict__ ign,
                          const int* __restrict__ offs, uint64_t* wkeys, uint64_t* skeys) {
  __shared__ int ls[NCLS], lw[NCLS];
  int t = threadIdx.x, pg = blockIdx.x;
  if (t < NCLS) {
    ls[t] = offs[pg * NCLS + t];
    lw[t] = offs[NBLK2 * NCLS + pg * NCLS + t];
  }
  __syncthreads();
  int n0 = pg * 512 + t * 2;
  int2   sg = *(const int2*)(seg + n0);
  int2   ig = *(const int2*)(ign + n0);
  float2 pr = *(const float2*)(prob + n0);
  float dw[2] = {0,0}, nw[2] = {0,0}, ds[2] = {0,0}, ns[2] = {0,0};
#pragma unroll
  for (int cc = 0; cc < NCC; ++cc) {
    const float4* pp = (const float4*)part + ((size_t)cc * NPIX + n0);
#pragma unroll
    for (int i = 0; i < 2; ++i) {
      float4 v = pp[i];
      dw[i] += v.x; nw[i] += v.y; ds[i] += v.z; ns[i] += v.w;
    }
  }
  int   sga[2] = {sg.x, sg.y};
  int   iga[2] = {ig.x, ig.y};
  float pra[2] = {pr.x, pr.y};
#pragma unroll
  for (int i = 0; i < 2; ++i) {
    if (iga[i] != 255) {
      int q = sga[i];
      float sim_s = ds[i] / fmaxf(sqrtf(ns[i]), EPSV);
      int pos = atomicAdd(&ls[q], 1);
      if (pos < CAP_S) skeys[(size_t)q * CAP_S + pos] = pack_key(-sim_s, (unsigned)(n0 + i));
      if (pra[i] > 0.95f) {
        float sim_w = dw[i] / fmaxf(sqrtf(nw[i]), EPSV);
        int pw = atomicAdd(&lw[q], 1);
        if (pw < CAP_W) wkeys[(size_t)q * CAP_W + pw] = pack_key(sim_w, (unsigned)(n0 + i));
      }
    }
  }
}

// ---------------- top-256 select (cutoff-filtered bitonic), 256 threads ----------------
__device__ void select_topk(const uint64_t* __restrict__ list, int cnt,
                            uint64_t* T, uint64_t* P, int* pcnt, int* woff) {
  int t = threadIdx.x;
  T[t] = ~0ull;
  if (t == 0) *pcnt = 0;
  __syncthreads();
  for (int base = 0; base < cnt; base += 256) {
    uint64_t key = (base + t < cnt) ? list[base + t] : ~0ull;
    uint64_t cutoff = T[KSEL - 1];
    bool pred = key < cutoff;
    unsigned long long mask = __ballot(pred);
    int wid = t >> 6, lane = t & 63;
    if (lane == 0) woff[wid] = __popcll(mask);
    int prefix = __popcll(mask & ((1ull << lane) - 1ull));
    __syncthreads();
    int off = 0;
    for (int w2 = 0; w2 < wid; ++w2) off += woff[w2];
    int total = woff[0] + woff[1] + woff[2] + woff[3];
    int old = *pcnt;
    if (pred) P[old + off + prefix] = key;
    int newc = old + total;
    __syncthreads();
    if (t == 0) *pcnt = newc;
    bool last = (base + 256 >= cnt);
    if (newc >= KSEL || (last && newc > 0)) {
      for (int i2 = t; i2 < 2 * KSEL; i2 += 256)
        if (i2 >= newc) P[i2] = ~0ull;
      for (unsigned size = 2; size <= 2 * KSEL; size <<= 1) {
        for (unsigned stride = size >> 1; stride > 0; stride >>= 1) {
          __syncthreads();
          unsigned lo = stride - 1;
          unsigned i = (((unsigned)t & ~lo) << 1) | ((unsigned)t & lo);
          unsigned j = i | stride;
          uint64_t a = P[i], b = P[j];
          bool up = ((i & size) == 0);
          if ((a > b) == up) { P[i] = b; P[j] = a; }
        }
      }
      __syncthreads();
      uint64_t a = T[t], b = P[KSEL - 1 - t];
      T[t] = a < b ? a : b;
      for (unsigned stride = KSEL / 2; stride > 0; stride >>= 1) {
        __syncthreads();
        if (((unsigned)t & stride) == 0) {
          uint64_t x = T[t], y = T[t + stride];
          if (x > y) { T[t] = y; T[t + stride] = x; }
        }
      }
      __syncthreads();
      if (t == 0) *pcnt = 0;
      __syncthreads();
    } else {
      __syncthreads();
    }
  }
}

// ---------------- K2: weak top-16 (full) + strong top-256 (partitioned) ----------------
__global__ void k2_topk(const uint64_t* __restrict__ wkeys, const uint64_t* __restrict__ skeys,
                        const int* wcnt, const int* scnt,
                        uint64_t* psel, int* idxw, int* kwv, int* nwv) {
  __shared__ uint64_t T[KSEL];
  __shared__ uint64_t P[2 * KSEL];
  __shared__ int pcnt;
  __shared__ int woff[4];
  int bid = blockIdx.x, t = threadIdx.x;
  if (bid < NCLS * NPART) {
    int k = bid / NPART, p = bid % NPART;
    int cnt = min(scnt[k], CAP_S);
    int chunk = (cnt + NPART - 1) / NPART;
    int lo = p * chunk;
    int hi = min(lo + chunk, cnt);
    int c = hi > lo ? hi - lo : 0;
    select_topk(skeys + (size_t)k * CAP_S + lo, c, T, P, &pcnt, woff);
    psel[((size_t)k * NPART + p) * KSEL + t] = T[t];
  } else {
    int k = bid - NCLS * NPART;
    int cnt_total = wcnt[k];
    int cnt = min(cnt_total, CAP_W);
    select_topk(wkeys + (size_t)k * CAP_W, cnt, T, P, &pcnt, woff);
    if (t < 16) idxw[k * 16 + t] = (int)(unsigned)(T[t] & 0xFFFFFFFFull);
    if (t == 0) { nwv[k] = cnt_total; kwv[k] = min(cnt_total, 16); }
  }
}

// ---------------- K2m: merge 8 sorted 256-lists -> top-256 via min-merge + bitonic clean ----------------
// Each input list is sorted ascending. Repeated: C[i] = min(A[i], B[255-i]) gives the
// smallest 256 of the union as a bitonic sequence; clean (8 stages) re-sorts ascending.
__global__ void k2m_merge(const uint64_t* __restrict__ psel, const int* scnt,
                          int* idxs, int* ksv, int* nsv) {
  int k = blockIdx.x, t = threadIdx.x;
  __shared__ uint64_t M[NPART * KSEL];   // 2048
  __shared__ uint64_t M2[4 * KSEL];      // 1024
  for (int i = t; i < NPART * KSEL; i += 256) M[i] = psel[(size_t)k * NPART * KSEL + i];
  __syncthreads();
  // round 1: 8 lists -> 4
#pragma unroll
  for (int p = 0; p < 4; ++p) {
    uint64_t a = M[p * 512 + t], b = M[p * 512 + 511 - t];
    M2[p * 256 + t] = a < b ? a : b;
  }
  for (int str = 128; str > 0; str >>= 1) {
    __syncthreads();
    for (int q = t; q < 4 * 128; q += 256) {
      int list = q >> 7, r = q & 127;
      int i = ((r & ~(str - 1)) << 1) | (r & (str - 1));
      int ai = list * 256 + i, bi = ai + str;
      uint64_t x = M2[ai], y = M2[bi];
      if (x > y) { M2[ai] = y; M2[bi] = x; }
    }
  }
  __syncthreads();
  // round 2: 4 lists -> 2
#pragma unroll
  for (int p = 0; p < 2; ++p) {
    uint64_t a = M2[p * 512 + t], b = M2[p * 512 + 511 - t];
    M[p * 256 + t] = a < b ? a : b;
  }
  for (int str = 128; str > 0; str >>= 1) {
    __syncthreads();
    {
      int q = t;  // 2*128 = 256 pairs
      int list = q >> 7, r = q & 127;
      int i = ((r & ~(str - 1)) << 1) | (r & (str - 1));
      int ai = list * 256 + i, bi = ai + str;
      uint64_t x = M[ai], y = M[bi];
      if (x > y) { M[ai] = y; M[bi] = x; }
    }
  }
  __syncthreads();
  // round 3: 2 lists -> 1
  {
    uint64_t a = M[t], b = M[511 - t];
    M2[t] = a < b ? a : b;
  }
  for (int str = 128; str > 0; str >>= 1) {
    __syncthreads();
    if (t < 128) {
      int r = t;
      int i = ((r & ~(str - 1)) << 1) | (r & (str - 1));
      uint64_t x = M2[i], y = M2[i + str];
      if (x > y) { M2[i] = y; M2[i + str] = x; }
    }
  }
  __syncthreads();
  idxs[k * KSEL + t] = (int)(unsigned)(M2[t] & 0xFFFFFFFFull);
  if (t == 0) { int c = scnt[k]; nsv[k] = c; ksv[k] = c < KSEL ? c : KSEL; }
}

// ---------------- K3a: gather + normalize selected vectors into dense buffers ----------------
// grid ((KSEL+16)/4, NCLS): 4 slots per block -> 4 independent strided loads per thread.
__global__ void k3a_gather(const float* __restrict__ fw, const float* __restrict__ fs,
                           const int* __restrict__ idxw, const int* __restrict__ idxs,
                           const int* __restrict__ kwv, const int* __restrict__ ksv,
                           float* dw_dense, float* ds_dense) {
  int k = blockIdx.y;
  int s0 = blockIdx.x * 4;
  int t = threadIdx.x;
  int wid = t >> 6, lane = t & 63;
  float v[4];
  bool strong[4];
  int slot_[4];
#pragma unroll
  for (int j = 0; j < 4; ++j) {
    int slot = s0 + j;
    slot_[j] = slot;
    strong[j] = slot < KSEL;
    bool ok;
    int n = 0;
    if (strong[j]) {
      ok = slot < ksv[k];
      if (ok) n = idxs[k * KSEL + slot];
    } else {
      int i = slot - KSEL;
      ok = i < kwv[k];
      int rank = i > 0 ? i - 1 : 0;  // ranks = max(arange(16)-1, 0)
      if (ok) n = idxw[k * 16 + rank];
    }
    v[j] = 0.0f;
    if (ok) {
      int b = n >> 14, hw = n & (HWSZ - 1);
      const float* f = strong[j] ? fs : fw;
      v[j] = f[(size_t)(b * CDIM + t) * HWSZ + hw];
    }
  }
  __shared__ float wsh[4][4];  // [wave][slot]
  float s[4];
#pragma unroll
  for (int j = 0; j < 4; ++j) {
    s[j] = v[j] * v[j];
    for (int o = 32; o > 0; o >>= 1) s[j] += __shfl_down(s[j], o, 64);
  }
  if (lane == 0) {
#pragma unroll
    for (int j = 0; j < 4; ++j) wsh[wid][j] = s[j];
  }
  __syncthreads();
#pragma unroll
  for (int j = 0; j < 4; ++j) {
    float tot = wsh[0][j] + wsh[1][j] + wsh[2][j] + wsh[3][j];
    float inv = 1.0f / fmaxf(sqrtf(tot), EPSV);
    float out = v[j] * inv;
    if (strong[j]) ds_dense[((size_t)k * KSEL + slot_[j]) * CDIM + t] = out;
    else           dw_dense[((size_t)k * 16 + (slot_[j] - KSEL)) * CDIM + t] = out;
  }
}

// ---------------- K3b: cosm, per-row max, per-class sum ----------------
__global__ void k3b_loss(const float* __restrict__ dw_dense, const float* __restrict__ ds_dense,
                         const int* kwv, const int* ksv, const int* nwv, const int* nsv,
                         float* simsum, int* countk) {
  int k = blockIdx.x, t = threadIdx.x;
  int wid = t >> 6, lane = t & 63;
  __shared__ float wn[16 * CDIM];
  __shared__ float wred[4][16];
  for (int i = t; i < 16 * CDIM; i += 256) wn[i] = dw_dense[(size_t)k * 16 * CDIM + i];
  __syncthreads();
  int ks_ = ksv[k], kw_ = kwv[k];
  bool ok = (nwv[k] > 0) && (nsv[k] > 0);
  float dots[16];
#pragma unroll
  for (int i = 0; i < 16; ++i) dots[i] = 0.0f;
  bool jv = ok && (t < ks_);
  if (jv) {
    const float4* sp = (const float4*)(ds_dense + ((size_t)k * KSEL + t) * CDIM);
    for (int c4 = 0; c4 < CDIM / 4; ++c4) {
      float4 v = sp[c4];
#pragma unroll
      for (int i = 0; i < 16; ++i) {
        float4 w = ((const float4*)(wn + i * CDIM))[c4];
        dots[i] = fmaf(v.x, w.x, dots[i]);
        dots[i] = fmaf(v.y, w.y, dots[i]);
        dots[i] = fmaf(v.z, w.z, dots[i]);
        dots[i] = fmaf(v.w, w.w, dots[i]);
      }
    }
  }
#pragma unroll
  for (int i = 0; i < 16; ++i) {
    float v = jv ? dots[i] : NEGV;
    for (int o = 32; o > 0; o >>= 1) v = fmaxf(v, __shfl_down(v, o, 64));
    if (lane == 0) wred[wid][i] = v;
  }
  __syncthreads();
  if (t == 0) {
    float csum = 0.0f;
    for (int i = 0; i < kw_; ++i) {
      float m = fmaxf(fmaxf(wred[0][i], wred[1][i]), fmaxf(wred[2][i], wred[3][i]));
      csum += m;
    }
    simsum[k] = ok ? csum : 0.0f;
    countk[k] = ok ? ks_ : 0;
  }
}

// ---------------- K4: memory bank update + loss ----------------
__global__ void k4_final(const float* __restrict__ mb, const float* __restrict__ wsum,
                         const int* __restrict__ nwv, const float* __restrict__ simsum,
                         const int* __restrict__ countk, float* out) {
  int k = blockIdx.x, t = threadIdx.x;
  float p = mb[k * CDIM + t];
  float o = p;
  int nw = nwv[k];
  if (nw > 0) {
    float mean = wsum[k * CDIM + t] / (float)nw;
    o = 0.99f * p + 0.01f * mean;
  }
  out[1 + k * CDIM + t] = o;
  if (k == 0 && t == 0) {
    float ss = 0.0f;
    int cc = 0;
    for (int q = 0; q < NCLS; ++q) { ss += simsum[q]; cc += countk[q]; }
    out[0] = (cc > 0) ? (1.0f - ss / (float)cc) : 0.0f;
  }
}

extern "C" void kernel_launch(void* const* d_in, const int* in_sizes, int n_in,
                              void* d_out, int out_size, void* d_ws, size_t ws_size,
                              hipStream_t stream) {
  const float* fw   = (const float*)d_in[0];
  const float* fs   = (const float*)d_in[1];
  const float* prob = (const float*)d_in[2];
  const float* mb   = (const float*)d_in[3];
  const int*   seg  = (const int*)d_in[4];
  const int*   ign  = (const int*)d_in[5];
  float* out = (float*)d_out;

  char* ws = (char*)d_ws;
  size_t off = 0;
  auto alloc = [&](size_t bytes) -> char* {
    char* p = ws + off;
    off = (off + bytes + 255) & ~(size_t)255;
    return p;
  };
  float*    pn       = (float*)alloc(NCLS * CDIM * 4);
  float*    wsum     = (float*)alloc(NCLS * CDIM * 4);
  int*      wcnt     = (int*)alloc(NCLS * 4);
  int*      scnt     = (int*)alloc(NCLS * 4);
  int*      idxw     = (int*)alloc(NCLS * 16 * 4);
  int*      idxs     = (int*)alloc(NCLS * KSEL * 4);
  int*      kwv      = (int*)alloc(NCLS * 4);
  int*      ksv      = (int*)alloc(NCLS * 4);
  int*      nwv      = (int*)alloc(NCLS * 4);
  int*      nsv      = (int*)alloc(NCLS * 4);
  float*    simsum   = (float*)alloc(NCLS * 4);
  int*      countk   = (int*)alloc(NCLS * 4);
  int*      cnts     = (int*)alloc(2 * NBLK2 * NCLS * 4);
  int*      offs     = (int*)alloc(2 * NBLK2 * NCLS * 4);
  uint64_t* wkeys    = (uint64_t*)alloc((size_t)NCLS * CAP_W * 8);
  uint64_t* skeys    = (uint64_t*)alloc((size_t)NCLS * CAP_S * 8);
  uint64_t* psel     = (uint64_t*)alloc((size_t)NCLS * NPART * KSEL * 8);
  float*    dw_dense = (float*)alloc((size_t)NCLS * 16 * CDIM * 4);
  float*    ds_dense = (float*)alloc((size_t)NCLS * KSEL * CDIM * 4);
  float*    part     = (float*)alloc((size_t)NCC * NPIX * 4 * 4);  // 16.8 MB
  (void)in_sizes; (void)n_in; (void)out_size; (void)ws_size;

  k0_init<<<NCLS, 256, 0, stream>>>(mb, pn, wsum);
  k1a_stream<<<dim3(NPG, NCC), 256, 0, stream>>>(fw, fs, prob, seg, ign, pn,
                                                 part, wsum);
  k1c_count<<<NBLK2, 256, 0, stream>>>(prob, seg, ign, cnts);
  ks_scan<<<1, 256, 0, stream>>>(cnts, offs, scnt, wcnt);
  k1b_write<<<NBLK2, 256, 0, stream>>>(part, prob, seg, ign, offs, wkeys, skeys);
  k2_topk<<<NCLS * NPART + NCLS, 256, 0, stream>>>(wkeys, skeys, wcnt, scnt,
                                                   psel, idxw, kwv, nwv);
  k2m_merge<<<NCLS, 256, 0, stream>>>(psel, scnt, idxs, ksv, nsv);
  k3a_gather<<<dim3((KSEL + 16) / 4, NCLS), 256, 0, stream>>>(fw, fs, idxw, idxs, kwv, ksv,
                                                              dw_dense, ds_dense);
  k3b_loss<<<NCLS, 256, 0, stream>>>(dw_dense, ds_dense, kwv, ksv, nwv, nsv,
                                     simsum, countk);
  k4_final<<<NCLS, 256, 0, stream>>>(mb, wsum, nwv, simsum, countk, out);
}